// Round 10
// baseline (110.002 us; speedup 1.0000x reference)
//
#include <hip/hip_runtime.h>
#include <math.h>

#define NROWS 4096
#define VCOLS 32000
#define NV4   (VCOLS / 4)     // 8000 float4 per row

typedef float f32x4 __attribute__((ext_vector_type(4)));

// Constants from reference: LS=0.1, CONF=0.9, SM=0.1/31999
constexpr float CONF_F   = 0.9f;
constexpr float SM_F     = 0.1f / 31999.0f;          // 3.1250977e-06
constexpr float KL_CONST = -1.36242896f;             // 0.9*ln(0.9) + 0.1*ln(SM)
constexpr float COEF_T   = CONF_F - SM_F;            // weight on logp[target]

// ---- kernel 1: init first-occurrence table ----
__global__ void k_init(int* __restrict__ ft32) {
    int v = blockIdx.x * blockDim.x + threadIdx.x;
    if (v < VCOLS) ft32[v] = NROWS;     // sentinel: never a candidate
}

// ---- kernel 2: first occurrence via atomicMin ----
__global__ void k_scatter(const int* __restrict__ target,
                          int* __restrict__ ft32) {
    int j = blockIdx.x * blockDim.x + threadIdx.x;
    if (j < NROWS) {
        int t  = target[j];
        int tc = (t != -1) ? t : 0;     // tgt = where(valid, target, PAD)
        // token 0 (PAD) excluded from neg targets (neg[:,0]=0): never mark.
        if (tc != 0) atomicMin(&ft32[tc], j);
    }
}

// ---- kernel 3: pack table to u16 (values <= 4096) ----
__global__ void k_pack(const int* __restrict__ ft32,
                       unsigned short* __restrict__ ft16) {
    int v = blockIdx.x * blockDim.x + threadIdx.x;
    if (v < VCOLS) ft16[v] = (unsigned short)ft32[v];
}

// ---- kernel 4: fused single-pass row kernel, distance-2 pipeline ----
// One block per row. Rotating 3-slot (A/B/C) pair pipeline: the loop issues
// slot C's 4 loads, then processes slot A (loaded 2 iterations ago) ->
// steady state 8 loads in flight per wave. Branchless online rescale once
// per 8 floats. Candidate logits go to deterministic LDS slots
// cand[ft16[v]] (unique writer per slot; ft16[0]==NROWS).
__global__ __launch_bounds__(256)
void k_main(const float* __restrict__ X,
            const int*   __restrict__ target,
            const unsigned short* __restrict__ ft16,
            float* __restrict__ kl_rows,
            float* __restrict__ custom_rows) {
    const int i   = blockIdx.x;
    const int tid = threadIdx.x;

    __shared__ float cand[NROWS];       // candidate logits by first-occ pos (16 KB)
    __shared__ float rm[256], rz[256], rs[256];
    __shared__ float s_logZ, s_xt;

    const int t = target[i];
    if (t == -1) {
        if (tid == 0) { kl_rows[i] = 0.0f; custom_rows[i] = 0.0f; }
        return;
    }
    const int    mytgt = t;                         // valid -> tgt == target
    const float* row   = X + (size_t)i * VCOLS;

    if (tid == 0) s_xt = row[mytgt];                // gold logit, once
    for (int j = tid; j < i; j += 256) cand[j] = -INFINITY;
    __syncthreads();

    const f32x4* row4 = (const f32x4*)row;          // 16B aligned (stride 128000B)
    const int2*  ft2  = (const int2*)ft16;          // 4 u16 per f32x4

    float m = -INFINITY, Z = 0.0f, sx = 0.0f;

#define MAX4(xx_) fmaxf(fmaxf((xx_).x, (xx_).y), fmaxf((xx_).z, (xx_).w))
#define SCAT(xx_, ff_, ee_) do {                                              \
        int base_ = (ee_) * 4;                                                \
        int a0_ = (ff_).x & 0xFFFF, a1_ = (int)(((unsigned)(ff_).x) >> 16);   \
        int a2_ = (ff_).y & 0xFFFF, a3_ = (int)(((unsigned)(ff_).y) >> 16);   \
        unsigned d_ = (unsigned)(mytgt - base_);                              \
        if (a0_ < i && d_ != 0u) cand[a0_] = (xx_).x;                         \
        if (a1_ < i && d_ != 1u) cand[a1_] = (xx_).y;                         \
        if (a2_ < i && d_ != 2u) cand[a2_] = (xx_).z;                         \
        if (a3_ < i && d_ != 3u) cand[a3_] = (xx_).w;                         \
    } while (0)
#define CHUNK(xa_, fa_, xb_, fb_, ea_) do {                                   \
        float cm_ = fmaxf(MAX4(xa_), MAX4(xb_));                              \
        float mn_ = fmaxf(m, cm_);                                            \
        Z *= __expf(m - mn_);            /* branchless rescale */             \
        m  = mn_;                                                             \
        Z += __expf((xa_).x - m) + __expf((xa_).y - m)                        \
           + __expf((xa_).z - m) + __expf((xa_).w - m)                        \
           + __expf((xb_).x - m) + __expf((xb_).y - m)                        \
           + __expf((xb_).z - m) + __expf((xb_).w - m);                       \
        sx += ((xa_).x + (xa_).y) + ((xa_).z + (xa_).w)                       \
            + ((xb_).x + (xb_).y) + ((xb_).z + (xb_).w);                      \
        SCAT(xa_, fa_, (ea_));                                                \
        SCAT(xb_, fb_, (ea_) + 256);                                          \
    } while (0)

    // prologue: slots A (e=tid) and B (e=tid+512) resident (tid+768 < 8000)
    int ea = tid;
    f32x4 xa0 = row4[ea];        int2 fa0 = ft2[ea];
    f32x4 xa1 = row4[ea + 256];  int2 fa1 = ft2[ea + 256];
    int eb = tid + 512;
    f32x4 xb0 = row4[eb];        int2 fb0 = ft2[eb];
    f32x4 xb1 = row4[eb + 256];  int2 fb1 = ft2[eb + 256];
    int en = tid + 1024;

    while (en + 256 < NV4) {            // next full pair exists
        // issue slot C's loads (distance-2 ahead of consumption)
        f32x4 xc0 = row4[en];        int2 fc0 = ft2[en];
        f32x4 xc1 = row4[en + 256];  int2 fc1 = ft2[en + 256];
        CHUNK(xa0, fa0, xa1, fa1, ea);  // consume A (loaded 2 iters ago)
        xa0 = xb0; fa0 = fb0; xa1 = xb1; fa1 = fb1; ea = eb;
        xb0 = xc0; fb0 = fc0; xb1 = xc1; fb1 = fc1; eb = en;
        en += 512;
    }
    CHUNK(xa0, fa0, xa1, fa1, ea);      // drain A
    CHUNK(xb0, fb0, xb1, fb1, eb);      // drain B

    for (; en < NV4; en += 256) {       // tail singles (0..1 per thread)
        f32x4 x_ = row4[en];  int2 f_ = ft2[en];
        float m4 = MAX4(x_);
        float mn = fmaxf(m, m4);
        Z *= __expf(m - mn);
        m  = mn;
        Z += __expf(x_.x - m) + __expf(x_.y - m)
           + __expf(x_.z - m) + __expf(x_.w - m);
        sx += (x_.x + x_.y) + (x_.z + x_.w);
        SCAT(x_, f_, en);
    }
#undef CHUNK
#undef SCAT
#undef MAX4

    rm[tid] = m; rz[tid] = Z; rs[tid] = sx;
    __syncthreads();
    for (int s = 128; s > 0; s >>= 1) {
        if (tid < s) {
            float m2 = rm[tid + s], z2 = rz[tid + s];
            float mm = fmaxf(rm[tid], m2);
            rz[tid]  = rz[tid] * __expf(rm[tid] - mm) + z2 * __expf(m2 - mm);
            rm[tid]  = mm;
            rs[tid] += rs[tid + s];
        }
        __syncthreads();
    }
    if (tid == 0) {
        float logZ    = rm[0] + __logf(rz[0]);
        s_logZ        = logZ;
        float logp_t  = s_xt - logZ;
        float sumlogp = rs[0] - (float)VCOLS * logZ;   // sum_j logp[i,j]
        kl_rows[i] = KL_CONST - COEF_T * logp_t - SM_F * sumlogp;
    }
    __syncthreads();
    const float logZ = s_logZ;

    // ---- unlikelihood tail over the candidate list ----
    float acc = 0.0f;
    for (int j = tid; j < i; j += 256) {
        float xv = cand[j];                 // -inf -> p=0 -> term 0
        float p  = __expf(xv - logZ);
        float om = fmaxf(1.0f - p, 1e-5f);
        acc -= __logf(om);
    }
    rs[tid] = acc;
    __syncthreads();
    for (int s = 128; s > 0; s >>= 1) {
        if (tid < s) rs[tid] += rs[tid + s];
        __syncthreads();
    }
    if (tid == 0) custom_rows[i] = rs[0];
}

// ---- kernel 5: deterministic final reduction ----
__global__ __launch_bounds__(1024)
void k_final(const float* __restrict__ kl_rows,
             const float* __restrict__ custom_rows,
             const int*   __restrict__ target,
             float* __restrict__ out) {
    __shared__ float sl[1024], sc[1024], sn[1024];
    int tid = threadIdx.x;
    float L = 0.0f, C = 0.0f, Nn = 0.0f;
    for (int j = tid; j < NROWS; j += 1024) {
        L += kl_rows[j];
        C += custom_rows[j];
        int t = target[j];
        if (t != -1 && t != 0) Nn += 1.0f;    // valid & (tgt != PAD)
    }
    sl[tid] = L; sc[tid] = C; sn[tid] = Nn;
    __syncthreads();
    for (int s = 512; s > 0; s >>= 1) {
        if (tid < s) { sl[tid] += sl[tid+s]; sc[tid] += sc[tid+s]; sn[tid] += sn[tid+s]; }
        __syncthreads();
    }
    if (tid == 0) {
        float norm = sn[0];
        out[0] = sl[0] / norm + 0.1f * sc[0] / norm;
    }
}

extern "C" void kernel_launch(void* const* d_in, const int* in_sizes, int n_in,
                              void* d_out, int out_size, void* d_ws, size_t ws_size,
                              hipStream_t stream) {
    const float* X      = (const float*)d_in[0];   // (N, V) float32
    const int*   target = (const int*)d_in[1];     // (N,)   int32
    float*       out    = (float*)d_out;

    char* ws = (char*)d_ws;
    int*            ft32        = (int*)           (ws);                    // 128000 B
    unsigned short* ft16        = (unsigned short*)(ws + 128000);           //  64000 B
    float*          kl_rows     = (float*)         (ws + 192000);           //  16384 B
    float*          custom_rows = (float*)         (ws + 192000 + 16384);   //  16384 B

    k_init   <<<(VCOLS + 255) / 256, 256, 0, stream>>>(ft32);
    k_scatter<<<(NROWS + 255) / 256, 256, 0, stream>>>(target, ft32);
    k_pack   <<<(VCOLS + 255) / 256, 256, 0, stream>>>(ft32, ft16);
    k_main   <<<NROWS,               256, 0, stream>>>(X, target, ft16,
                                                       kl_rows, custom_rows);
    k_final  <<<1,                  1024, 0, stream>>>(kl_rows, custom_rows, target, out);
}